// Round 5
// baseline (161566.162 us; speedup 1.0000x reference)
//
#include <hip/hip_runtime.h>
#include <hip/hip_fp16.h>

// ============================================================================
// Bidirectional 2-layer GRU (T=32768, C=64, H=256) + Gaussian heads (K=10).
//
//   recur_kernel v4: 2 blocks (fwd/bwd), 1024 threads (16 waves).
//   - BUILTIN MFMA only (round-1/2 validated numeric path; no inline-asm MFMA
//     -> compiler handles all XDL hazards).
//   - w_hh register-resident: 3 row-tiles/wave -> aw[3][8] = 96 VGPRs/wave,
//     total demand ~175 < 256 arch cap -> no AGPR shuttling (the round-1/2
//     slowdown: 192/384-reg weight arrays forced v_accvgpr_read per step).
//   - 2 raw s_barriers/step with lgkmcnt(0)-only drain (validated round 2);
//     global i_all loads / out stores stay in flight across barriers.
//   - i_all prefetched 4 steps ahead (4 rotating register sets, ~2800 cyc
//     cover vs ~900 cyc HBM latency).
//   - gates computed once by tid<256 (scalar, f32, hold carry in register).
//
// Workspace (~164 MB): xh@0 (4MB), iall_f@4MB (48MB), iall_b@52MB (48MB),
//                      out0@100MB (32MB), out1@132MB (32MB)
// ============================================================================

typedef _Float16 f16x8 __attribute__((ext_vector_type(8)));
typedef float    f32x4 __attribute__((ext_vector_type(4)));

#define T_LEN 32768
#define HDIM  256

// ---------------------------------------------------------------------------
__global__ void cvt_x_kernel(const float* __restrict__ x, __half* __restrict__ xh) {
    int i = (blockIdx.x * 256 + threadIdx.x) * 8;
    f32x4 a = *reinterpret_cast<const f32x4*>(x + i);
    f32x4 b = *reinterpret_cast<const f32x4*>(x + i + 4);
    f16x8 v;
#pragma unroll
    for (int j = 0; j < 4; ++j) { v[j] = (_Float16)a[j]; v[4 + j] = (_Float16)b[j]; }
    *reinterpret_cast<f16x8*>(xh + i) = v;
}

// ---------------------------------------------------------------------------
// C(M x 768) = A(M x K, f16) @ B(768 x K, f32)^T + bias, C stored f16.
// ---------------------------------------------------------------------------
__global__ __launch_bounds__(256, 1)
void gemm_f16_kernel(const __half* __restrict__ A,
                     const float* __restrict__ B0, const float* __restrict__ B1,
                     const float* __restrict__ bias0, const float* __restrict__ bias1,
                     __half* __restrict__ C0, __half* __restrict__ C1, int K) {
    const float* B    = blockIdx.z ? B1 : B0;
    const float* bias = blockIdx.z ? bias1 : bias0;
    __half*      C    = blockIdx.z ? C1 : C0;
    const int m0 = blockIdx.x * 128, n0 = blockIdx.y * 128;
    const int tid = threadIdx.x, lane = tid & 63, wv = tid >> 6;
    const int wm = (wv >> 1) * 64, wn = (wv & 1) * 64;
    const int qq = lane >> 4, r16 = lane & 15;

    __shared__ __align__(16) _Float16 As[128][40];
    __shared__ __align__(16) _Float16 Bs[128][40];

    f32x4 acc[4][4];
#pragma unroll
    for (int i = 0; i < 4; ++i)
#pragma unroll
        for (int j = 0; j < 4; ++j) acc[i][j] = (f32x4){0.f, 0.f, 0.f, 0.f};

    const int r = tid >> 1, seg = tid & 1;
    for (int k0 = 0; k0 < K; k0 += 32) {
        const f16x8* ap = reinterpret_cast<const f16x8*>(A + (size_t)(m0 + r) * K + k0 + 16 * seg);
        f16x8 a0 = ap[0], a1 = ap[1];
        const f32x4* bp = reinterpret_cast<const f32x4*>(B + (size_t)(n0 + r) * K + k0 + 16 * seg);
        f32x4 b0v = bp[0], b1v = bp[1], b2v = bp[2], b3v = bp[3];
        f16x8 bh0, bh1;
#pragma unroll
        for (int j = 0; j < 4; ++j) {
            bh0[j] = (_Float16)b0v[j]; bh0[4 + j] = (_Float16)b1v[j];
            bh1[j] = (_Float16)b2v[j]; bh1[4 + j] = (_Float16)b3v[j];
        }
        *reinterpret_cast<f16x8*>(&As[r][16 * seg])     = a0;
        *reinterpret_cast<f16x8*>(&As[r][16 * seg + 8]) = a1;
        *reinterpret_cast<f16x8*>(&Bs[r][16 * seg])     = bh0;
        *reinterpret_cast<f16x8*>(&Bs[r][16 * seg + 8]) = bh1;
        __syncthreads();

        f16x8 af[4], bf[4];
#pragma unroll
        for (int mi = 0; mi < 4; ++mi)
            af[mi] = *reinterpret_cast<const f16x8*>(&As[wm + 16 * mi + r16][8 * qq]);
#pragma unroll
        for (int ni = 0; ni < 4; ++ni)
            bf[ni] = *reinterpret_cast<const f16x8*>(&Bs[wn + 16 * ni + r16][8 * qq]);
#pragma unroll
        for (int mi = 0; mi < 4; ++mi)
#pragma unroll
            for (int ni = 0; ni < 4; ++ni)
                acc[mi][ni] = __builtin_amdgcn_mfma_f32_16x16x32_f16(af[mi], bf[ni], acc[mi][ni], 0, 0, 0);
        __syncthreads();
    }
#pragma unroll
    for (int mi = 0; mi < 4; ++mi)
#pragma unroll
        for (int ni = 0; ni < 4; ++ni)
#pragma unroll
            for (int rr = 0; rr < 4; ++rr) {
                int grow = m0 + wm + 16 * mi + 4 * qq + rr;
                int gcol = n0 + wn + 16 * ni + r16;
                C[(size_t)grow * 768 + gcol] = __float2half(acc[mi][ni][rr] + bias[gcol]);
            }
}

// ---------------------------------------------------------------------------
// Persistent GRU scan v4: 1024 threads, 16 waves, 3 row-tiles/wave (builtin
// MFMA, register-resident weights), 2 raw barriers/step, depth-4 prefetch.
// ---------------------------------------------------------------------------
struct X3 { __half r, z, g; };

#define LOAD_X(DST, TP)                                                \
    {                                                                  \
        const __half* ip = iall + (size_t)(TP) * 768;                  \
        if (tid < HDIM) {                                              \
            DST.r = ip[tid]; DST.z = ip[256 + tid]; DST.g = ip[512 + tid]; \
        }                                                              \
    }

#define GRU_STEP(XS, PB, TP, TPN)                                                 \
    {                                                                             \
        __half lxr = XS.r, lxz = XS.z, lxg = XS.g;  /* SSA copy of consumed set */\
        LOAD_X(XS, TPN);                            /* refill: used at TP+4 */    \
        const _Float16* hb = &hbuf[PB][0];                                        \
        f16x8 bf[8];                                                              \
        _Pragma("unroll")                                                         \
        for (int kc = 0; kc < 8; ++kc)                                            \
            bf[kc] = *reinterpret_cast<const f16x8*>(hb + kc * 32 + qq * 8);      \
        f32x4 acc[3];                                                             \
        _Pragma("unroll")                                                         \
        for (int i = 0; i < 3; ++i) acc[i] = (f32x4){0.f, 0.f, 0.f, 0.f};         \
        _Pragma("unroll")                                                         \
        for (int kc = 0; kc < 8; ++kc)                                            \
            _Pragma("unroll")                                                     \
            for (int i = 0; i < 3; ++i)                                           \
                acc[i] = __builtin_amdgcn_mfma_f32_16x16x32_f16(aw[i][kc], bf[kc], acc[i], 0, 0, 0); \
        if (r16 == 0) {                                                           \
            _Pragma("unroll")                                                     \
            for (int i = 0; i < 3; ++i)                                           \
                *reinterpret_cast<f32x4*>(&pre[16 * (3 * wv + i) + 4 * qq]) = acc[i]; \
        }                                                                         \
        asm volatile("s_waitcnt lgkmcnt(0)" ::: "memory");                        \
        __builtin_amdgcn_s_barrier();                                             \
        if (tid < HDIM) {                                                         \
            float pr = pre[tid], pz = pre[256 + tid], pg = pre[512 + tid];        \
            float ar = __half2float(lxr) + pr;                                    \
            float az = __half2float(lxz) + pz;                                    \
            float rg = 1.f / (1.f + __expf(-ar));                                 \
            float zg = 1.f / (1.f + __expf(-az));                                 \
            float ag = __half2float(lxg) + rg * (pg + cbn);                       \
            float e2 = __expf(-2.f * fabsf(ag));                                  \
            float th = (1.f - e2) / (1.f + e2);                                   \
            float gg = (ag >= 0.f) ? th : -th;                                    \
            float hn = (1.f - zg) * gg + zg * hold;                               \
            hold = hn;                                                            \
            __half hh = __float2half(hn);                                         \
            hbuf[(PB) ^ 1][tid] = (_Float16)hh;                                   \
            out[(size_t)(TP) * 512 + colofs + tid] = hh;                          \
        }                                                                         \
        asm volatile("s_waitcnt lgkmcnt(0)" ::: "memory");                        \
        __builtin_amdgcn_s_barrier();                                             \
    }

__global__ __launch_bounds__(1024, 1)
void recur_kernel(const float* __restrict__ whh_f, const float* __restrict__ whh_b,
                  const float* __restrict__ bn_f, const float* __restrict__ bn_b,
                  const __half* __restrict__ iall_f, const __half* __restrict__ iall_b,
                  __half* __restrict__ out /* T x 512 */) {
    const int dir = blockIdx.x;
    const float*  whh  = dir ? whh_b  : whh_f;
    const float*  bn   = dir ? bn_b   : bn_f;
    const __half* iall = dir ? iall_b : iall_f;
    const int colofs   = dir ? HDIM : 0;

    const int tid = threadIdx.x;           // 0..1023
    const int ln  = tid & 63;
    const int wv  = tid >> 6;              // wave 0..15
    const int qq  = ln >> 4;               // 0..3
    const int r16 = ln & 15;

    __shared__ __align__(16) _Float16 hbuf[2][HDIM];   // shared h, double-buffered
    __shared__ __align__(16) float    pre[768];        // preacts (2-barrier safe)

    // ---- w_hh -> 24 A-fragments per wave (96 VGPR, register-resident) ----
    f16x8 aw[3][8];
#pragma unroll
    for (int i = 0; i < 3; ++i) {
        int row = 16 * (3 * wv + i) + r16;
        const float* wr = whh + (size_t)row * HDIM + 8 * qq;
#pragma unroll
        for (int kc = 0; kc < 8; ++kc) {
            const f32x4* p4 = reinterpret_cast<const f32x4*>(wr + 32 * kc);
            f32x4 w0 = p4[0], w1 = p4[1];
            f16x8 v;
#pragma unroll
            for (int j = 0; j < 4; ++j) { v[j] = (_Float16)w0[j]; v[4 + j] = (_Float16)w1[j]; }
            aw[i][kc] = v;
        }
    }

    float cbn = 0.f, hold = 0.f;
    if (tid < HDIM) {
        cbn = bn[tid];
        hbuf[0][tid] = (_Float16)0.f;
    }
    __syncthreads();

    // depth-4 prefetch: 4 rotating sets
    X3 s0, s1, s2, s3;
    {
        const int t0 = dir ? T_LEN - 1 : 0;
        const int t1 = dir ? T_LEN - 2 : 1;
        const int t2 = dir ? T_LEN - 3 : 2;
        const int t3 = dir ? T_LEN - 4 : 3;
        LOAD_X(s0, t0); LOAD_X(s1, t1); LOAD_X(s2, t2); LOAD_X(s3, t3);
    }

    for (int ts = 0; ts < T_LEN; ts += 4) {
        const int c4 = (ts + 4 < T_LEN) ? ts + 4 : T_LEN - 1;  // clamped (tail unused)
        const int c5 = (ts + 5 < T_LEN) ? ts + 5 : T_LEN - 1;
        const int c6 = (ts + 6 < T_LEN) ? ts + 6 : T_LEN - 1;
        const int c7 = (ts + 7 < T_LEN) ? ts + 7 : T_LEN - 1;
        const int tp0 = dir ? (T_LEN - 1 - ts)     : ts;
        const int tp1 = dir ? (T_LEN - 2 - ts)     : ts + 1;
        const int tp2 = dir ? (T_LEN - 3 - ts)     : ts + 2;
        const int tp3 = dir ? (T_LEN - 4 - ts)     : ts + 3;
        const int tn0 = dir ? (T_LEN - 1 - c4)     : c4;
        const int tn1 = dir ? (T_LEN - 1 - c5)     : c5;
        const int tn2 = dir ? (T_LEN - 1 - c6)     : c6;
        const int tn3 = dir ? (T_LEN - 1 - c7)     : c7;

        GRU_STEP(s0, 0, tp0, tn0);
        GRU_STEP(s1, 1, tp1, tn1);
        GRU_STEP(s2, 0, tp2, tn2);
        GRU_STEP(s3, 1, tp3, tn3);
    }
}

// ---------------------------------------------------------------------------
__device__ inline float softplus_f(float x) {
    return (x > 20.f) ? x : log1pf(__expf(x));
}

__global__ __launch_bounds__(256, 1)
void head_kernel(const __half* __restrict__ h1,
                 const float* __restrict__ mu_w, const float* __restrict__ mu_b,
                 const float* __restrict__ sg_w, const float* __restrict__ sg_b,
                 float* __restrict__ outp) {
    const int tid = threadIdx.x, lane = tid & 63, wv = tid >> 6;
    const int qq = lane >> 4, r16 = lane & 15;
    const int m0 = blockIdx.x * 128;

    __shared__ __align__(16) _Float16 Ws[32][520];
    __shared__ __align__(16) _Float16 Hs[128][40];

    {
        int rw = tid >> 3, c0 = (tid & 7) * 64;
        const float* src = (rw < 10) ? (mu_w + (size_t)rw * 512 + c0)
                         : (rw < 20) ? (sg_w + (size_t)(rw - 10) * 512 + c0) : nullptr;
        for (int cc = 0; cc < 64; cc += 8) {
            f16x8 hv;
            if (src) {
                f32x4 v0 = *reinterpret_cast<const f32x4*>(src + cc);
                f32x4 v1 = *reinterpret_cast<const f32x4*>(src + cc + 4);
#pragma unroll
                for (int j = 0; j < 4; ++j) { hv[j] = (_Float16)v0[j]; hv[4 + j] = (_Float16)v1[j]; }
            } else {
#pragma unroll
                for (int j = 0; j < 8; ++j) hv[j] = (_Float16)0.f;
            }
            *reinterpret_cast<f16x8*>(&Ws[rw][c0 + cc]) = hv;
        }
    }
    __syncthreads();

    f32x4 acc[2][2];
#pragma unroll
    for (int i = 0; i < 2; ++i)
#pragma unroll
        for (int j = 0; j < 2; ++j) acc[i][j] = (f32x4){0.f, 0.f, 0.f, 0.f};

    const int r = tid >> 1, seg = tid & 1;
    for (int kc = 0; kc < 16; ++kc) {
        const f16x8* hp = reinterpret_cast<const f16x8*>(h1 + (size_t)(m0 + r) * 512 + kc * 32 + 16 * seg);
        f16x8 h0 = hp[0], h1v = hp[1];
        *reinterpret_cast<f16x8*>(&Hs[r][16 * seg])     = h0;
        *reinterpret_cast<f16x8*>(&Hs[r][16 * seg + 8]) = h1v;
        __syncthreads();
        f16x8 af[2], bf[2];
#pragma unroll
        for (int mi = 0; mi < 2; ++mi)
            af[mi] = *reinterpret_cast<const f16x8*>(&Hs[wv * 32 + 16 * mi + r16][8 * qq]);
#pragma unroll
        for (int ni = 0; ni < 2; ++ni)
            bf[ni] = *reinterpret_cast<const f16x8*>(&Ws[16 * ni + r16][kc * 32 + 8 * qq]);
#pragma unroll
        for (int mi = 0; mi < 2; ++mi)
#pragma unroll
            for (int ni = 0; ni < 2; ++ni)
                acc[mi][ni] = __builtin_amdgcn_mfma_f32_16x16x32_f16(af[mi], bf[ni], acc[mi][ni], 0, 0, 0);
        __syncthreads();
    }

#pragma unroll
    for (int mi = 0; mi < 2; ++mi)
#pragma unroll
        for (int ni = 0; ni < 2; ++ni) {
            int ch = 16 * ni + r16;
#pragma unroll
            for (int rr = 0; rr < 4; ++rr) {
                int grow = m0 + wv * 32 + 16 * mi + 4 * qq + rr;
                float v = acc[mi][ni][rr];
                if (ch < 10) {
                    outp[(size_t)grow * 10 + ch] = v + mu_b[ch];
                } else if (ch < 20) {
                    outp[(size_t)T_LEN * 10 + (size_t)grow * 10 + (ch - 10)] = softplus_f(v + sg_b[ch - 10]);
                }
            }
        }
}

// ---------------------------------------------------------------------------
extern "C" void kernel_launch(void* const* d_in, const int* in_sizes, int n_in,
                              void* d_out, int out_size, void* d_ws, size_t ws_size,
                              hipStream_t stream) {
    const float* x      = (const float*)d_in[0];
    const float* wih_f0 = (const float*)d_in[1];
    const float* whh_f0 = (const float*)d_in[2];
    const float* b_f0   = (const float*)d_in[3];
    const float* bn_f0  = (const float*)d_in[4];
    const float* wih_b0 = (const float*)d_in[5];
    const float* whh_b0 = (const float*)d_in[6];
    const float* b_b0   = (const float*)d_in[7];
    const float* bn_b0  = (const float*)d_in[8];
    const float* wih_f1 = (const float*)d_in[9];
    const float* whh_f1 = (const float*)d_in[10];
    const float* b_f1   = (const float*)d_in[11];
    const float* bn_f1  = (const float*)d_in[12];
    const float* wih_b1 = (const float*)d_in[13];
    const float* whh_b1 = (const float*)d_in[14];
    const float* b_b1   = (const float*)d_in[15];
    const float* bn_b1  = (const float*)d_in[16];
    const float* mu_w   = (const float*)d_in[17];
    const float* mu_b   = (const float*)d_in[18];
    const float* sg_w   = (const float*)d_in[19];
    const float* sg_b   = (const float*)d_in[20];

    char* ws = (char*)d_ws;
    __half* xh     = (__half*)(ws);
    __half* iall_f = (__half*)(ws + (size_t)4 * 1024 * 1024);
    __half* iall_b = (__half*)(ws + (size_t)52 * 1024 * 1024);
    __half* out0   = (__half*)(ws + (size_t)100 * 1024 * 1024);
    __half* out1   = (__half*)(ws + (size_t)132 * 1024 * 1024);

    cvt_x_kernel<<<dim3((T_LEN * 64) / (256 * 8)), 256, 0, stream>>>(x, xh);
    gemm_f16_kernel<<<dim3(T_LEN / 128, 6, 2), 256, 0, stream>>>(xh, wih_f0, wih_b0, b_f0, b_b0, iall_f, iall_b, 64);
    recur_kernel<<<dim3(2), 1024, 0, stream>>>(whh_f0, whh_b0, bn_f0, bn_b0, iall_f, iall_b, out0);
    gemm_f16_kernel<<<dim3(T_LEN / 128, 6, 2), 256, 0, stream>>>(out0, wih_f1, wih_b1, b_f1, b_b1, iall_f, iall_b, 512);
    recur_kernel<<<dim3(2), 1024, 0, stream>>>(whh_f1, whh_b1, bn_f1, bn_b1, iall_f, iall_b, out1);
    head_kernel<<<dim3(T_LEN / 128), 256, 0, stream>>>(out1, mu_w, mu_b, sg_w, sg_b, (float*)d_out);
}

// Round 7
// 86067.010 us; speedup vs baseline: 1.8772x; 1.8772x over previous
//
#include <hip/hip_runtime.h>
#include <hip/hip_fp16.h>

// ============================================================================
// Bidirectional 2-layer GRU (T=32768, C=64, H=256) + Gaussian heads (K=10).
//
//   recur_kernel v6: 2 blocks (fwd/bwd), 512 threads (8 waves),
//   amdgpu_waves_per_eu(2,2).
//   KEY INSIGHT (r1/r2/r5 post-mortem): arch-VGPR file is 256/wave MAX
//   (v0-v255); beyond that values go to AGPRs, and builtin MFMA can't read
//   A/B from AGPR -> per-step v_accvgpr_read shuttle (the 3790-8100 cyc/step
//   disease). Weights need 1536 regs total -> 8 waves x 192 is the ONLY
//   resident layout. v6 squeezes the per-wave working set under 256:
//     aw[6][8] = 192 (weights)  + bf 4-slot window = 16  + acc = 24
//     + x-prefetch/addr/misc ~ 20   => ~252 <= 256.
//   - bf slots: preload kc0-3, reload slot after its use (WAR-safe; ~90 cyc
//     window + co-resident wave hides ds_read latency).
//   - builtin MFMA only (validated numerics, absmax 0.0039).
//   - 2 raw s_barriers/step, lgkmcnt(0)-only drain; i_all prefetch depth-2.
//
// Workspace (~164 MB): xh@0 (4MB), iall_f@4MB (48MB), iall_b@52MB (48MB),
//                      out0@100MB (32MB), out1@132MB (32MB)
// ============================================================================

typedef _Float16 f16x8 __attribute__((ext_vector_type(8)));
typedef float    f32x4 __attribute__((ext_vector_type(4)));

#define T_LEN 32768
#define HDIM  256

// ---------------------------------------------------------------------------
__global__ void cvt_x_kernel(const float* __restrict__ x, __half* __restrict__ xh) {
    int i = (blockIdx.x * 256 + threadIdx.x) * 8;
    f32x4 a = *reinterpret_cast<const f32x4*>(x + i);
    f32x4 b = *reinterpret_cast<const f32x4*>(x + i + 4);
    f16x8 v;
#pragma unroll
    for (int j = 0; j < 4; ++j) { v[j] = (_Float16)a[j]; v[4 + j] = (_Float16)b[j]; }
    *reinterpret_cast<f16x8*>(xh + i) = v;
}

// ---------------------------------------------------------------------------
// C(M x 768) = A(M x K, f16) @ B(768 x K, f32)^T + bias, C stored f16.
// ---------------------------------------------------------------------------
__global__ __launch_bounds__(256, 1)
void gemm_f16_kernel(const __half* __restrict__ A,
                     const float* __restrict__ B0, const float* __restrict__ B1,
                     const float* __restrict__ bias0, const float* __restrict__ bias1,
                     __half* __restrict__ C0, __half* __restrict__ C1, int K) {
    const float* B    = blockIdx.z ? B1 : B0;
    const float* bias = blockIdx.z ? bias1 : bias0;
    __half*      C    = blockIdx.z ? C1 : C0;
    const int m0 = blockIdx.x * 128, n0 = blockIdx.y * 128;
    const int tid = threadIdx.x, lane = tid & 63, wv = tid >> 6;
    const int wm = (wv >> 1) * 64, wn = (wv & 1) * 64;
    const int qq = lane >> 4, r16 = lane & 15;

    __shared__ __align__(16) _Float16 As[128][40];
    __shared__ __align__(16) _Float16 Bs[128][40];

    f32x4 acc[4][4];
#pragma unroll
    for (int i = 0; i < 4; ++i)
#pragma unroll
        for (int j = 0; j < 4; ++j) acc[i][j] = (f32x4){0.f, 0.f, 0.f, 0.f};

    const int r = tid >> 1, seg = tid & 1;
    for (int k0 = 0; k0 < K; k0 += 32) {
        const f16x8* ap = reinterpret_cast<const f16x8*>(A + (size_t)(m0 + r) * K + k0 + 16 * seg);
        f16x8 a0 = ap[0], a1 = ap[1];
        const f32x4* bp = reinterpret_cast<const f32x4*>(B + (size_t)(n0 + r) * K + k0 + 16 * seg);
        f32x4 b0v = bp[0], b1v = bp[1], b2v = bp[2], b3v = bp[3];
        f16x8 bh0, bh1;
#pragma unroll
        for (int j = 0; j < 4; ++j) {
            bh0[j] = (_Float16)b0v[j]; bh0[4 + j] = (_Float16)b1v[j];
            bh1[j] = (_Float16)b2v[j]; bh1[4 + j] = (_Float16)b3v[j];
        }
        *reinterpret_cast<f16x8*>(&As[r][16 * seg])     = a0;
        *reinterpret_cast<f16x8*>(&As[r][16 * seg + 8]) = a1;
        *reinterpret_cast<f16x8*>(&Bs[r][16 * seg])     = bh0;
        *reinterpret_cast<f16x8*>(&Bs[r][16 * seg + 8]) = bh1;
        __syncthreads();

        f16x8 af[4], bf[4];
#pragma unroll
        for (int mi = 0; mi < 4; ++mi)
            af[mi] = *reinterpret_cast<const f16x8*>(&As[wm + 16 * mi + r16][8 * qq]);
#pragma unroll
        for (int ni = 0; ni < 4; ++ni)
            bf[ni] = *reinterpret_cast<const f16x8*>(&Bs[wn + 16 * ni + r16][8 * qq]);
#pragma unroll
        for (int mi = 0; mi < 4; ++mi)
#pragma unroll
            for (int ni = 0; ni < 4; ++ni)
                acc[mi][ni] = __builtin_amdgcn_mfma_f32_16x16x32_f16(af[mi], bf[ni], acc[mi][ni], 0, 0, 0);
        __syncthreads();
    }
#pragma unroll
    for (int mi = 0; mi < 4; ++mi)
#pragma unroll
        for (int ni = 0; ni < 4; ++ni)
#pragma unroll
            for (int rr = 0; rr < 4; ++rr) {
                int grow = m0 + wm + 16 * mi + 4 * qq + rr;
                int gcol = n0 + wn + 16 * ni + r16;
                C[(size_t)grow * 768 + gcol] = __float2half(acc[mi][ni][rr] + bias[gcol]);
            }
}

// ---------------------------------------------------------------------------
// Persistent GRU scan v6.
// ---------------------------------------------------------------------------
struct X3 { __half r, z, g; };

#define LOAD_X(DST, TP)                                                \
    {                                                                  \
        const __half* ip = iall + (size_t)(TP) * 768;                  \
        if (tid < HDIM) {                                              \
            DST.r = ip[tid]; DST.z = ip[256 + tid]; DST.g = ip[512 + tid]; \
        }                                                              \
    }

#define BF_LD(KC) (*reinterpret_cast<const f16x8*>(hb + (KC) * 32 + qq * 8))

#define MFMA6(KC, BB, CIN)                                                        \
    {                                                                             \
        _Pragma("unroll")                                                         \
        for (int i = 0; i < 6; ++i)                                               \
            acc[i] = __builtin_amdgcn_mfma_f32_16x16x32_f16(aw[i][KC], BB, CIN, 0, 0, 0); \
    }

#define GRU_STEP(XS, PB, TP, TPN)                                                 \
    {                                                                             \
        __half lxr = XS.r, lxz = XS.z, lxg = XS.g;  /* consume set, then refill */\
        LOAD_X(XS, TPN);                            /* used 2 steps later */      \
        const _Float16* hb = &hbuf[PB][0];                                        \
        f16x8 bb0 = BF_LD(0), bb1 = BF_LD(1), bb2 = BF_LD(2), bb3 = BF_LD(3);     \
        f32x4 acc[6];                                                             \
        MFMA6(0, bb0, czero);  bb0 = BF_LD(4);                                    \
        MFMA6(1, bb1, acc[i]); bb1 = BF_LD(5);                                    \
        MFMA6(2, bb2, acc[i]); bb2 = BF_LD(6);                                    \
        MFMA6(3, bb3, acc[i]); bb3 = BF_LD(7);                                    \
        MFMA6(4, bb0, acc[i]);                                                    \
        MFMA6(5, bb1, acc[i]);                                                    \
        MFMA6(6, bb2, acc[i]);                                                    \
        MFMA6(7, bb3, acc[i]);                                                    \
        if (r16 == 0) {                                                           \
            _Pragma("unroll")                                                     \
            for (int i = 0; i < 6; ++i)                                           \
                *reinterpret_cast<f32x4*>(&pre[16 * (6 * wv + i) + 4 * qq]) = acc[i]; \
        }                                                                         \
        asm volatile("s_waitcnt lgkmcnt(0)" ::: "memory");                        \
        __builtin_amdgcn_s_barrier();                                             \
        if (tid < HDIM) {                                                         \
            float pr = pre[tid], pz = pre[256 + tid], pg = pre[512 + tid];        \
            float ar = __half2float(lxr) + pr;                                    \
            float az = __half2float(lxz) + pz;                                    \
            float rg = 1.f / (1.f + __expf(-ar));                                 \
            float zg = 1.f / (1.f + __expf(-az));                                 \
            float ag = __half2float(lxg) + rg * (pg + cbn);                       \
            float e2 = __expf(-2.f * fabsf(ag));                                  \
            float th = (1.f - e2) / (1.f + e2);                                   \
            float gg = (ag >= 0.f) ? th : -th;                                    \
            float hn = (1.f - zg) * gg + zg * hold;                               \
            hold = hn;                                                            \
            __half hh = __float2half(hn);                                         \
            hbuf[(PB) ^ 1][tid] = (_Float16)hh;                                   \
            out[(size_t)(TP) * 512 + colofs + tid] = hh;                          \
        }                                                                         \
        asm volatile("s_waitcnt lgkmcnt(0)" ::: "memory");                        \
        __builtin_amdgcn_s_barrier();                                             \
    }

__global__ __launch_bounds__(512)
__attribute__((amdgpu_waves_per_eu(2, 2)))
void recur_kernel(const float* __restrict__ whh_f, const float* __restrict__ whh_b,
                  const float* __restrict__ bn_f, const float* __restrict__ bn_b,
                  const __half* __restrict__ iall_f, const __half* __restrict__ iall_b,
                  __half* __restrict__ out /* T x 512 */) {
    const int dir = blockIdx.x;
    const float*  whh  = dir ? whh_b  : whh_f;
    const float*  bn   = dir ? bn_b   : bn_f;
    const __half* iall = dir ? iall_b : iall_f;
    const int colofs   = dir ? HDIM : 0;

    const int tid = threadIdx.x;           // 0..511
    const int ln  = tid & 63;
    const int wv  = tid >> 6;              // wave 0..7
    const int qq  = ln >> 4;               // 0..3
    const int r16 = ln & 15;

    __shared__ __align__(16) _Float16 hbuf[2][HDIM];   // h, double-buffered
    __shared__ __align__(16) float    pre[768];        // preacts (2-barrier safe)

    // ---- w_hh -> 48 A-fragments per wave (192 VGPR, register-resident) ----
    f16x8 aw[6][8];
#pragma unroll
    for (int i = 0; i < 6; ++i) {
        int row = 16 * (6 * wv + i) + r16;
        const float* wr = whh + (size_t)row * HDIM + 8 * qq;
#pragma unroll
        for (int kc = 0; kc < 8; ++kc) {
            const f32x4* p4 = reinterpret_cast<const f32x4*>(wr + 32 * kc);
            f32x4 w0 = p4[0], w1 = p4[1];
            f16x8 v;
#pragma unroll
            for (int j = 0; j < 4; ++j) { v[j] = (_Float16)w0[j]; v[4 + j] = (_Float16)w1[j]; }
            aw[i][kc] = v;
        }
    }

    const f32x4 czero = (f32x4){0.f, 0.f, 0.f, 0.f};
    float cbn = 0.f, hold = 0.f;
    if (tid < HDIM) {
        cbn = bn[tid];
        hbuf[0][tid] = (_Float16)0.f;
    }
    __syncthreads();

    // depth-2 prefetch: 2 rotating sets, each refilled 2 steps ahead of use
    X3 s0, s1;
    {
        const int t0 = dir ? T_LEN - 1 : 0;
        const int t1 = dir ? T_LEN - 2 : 1;
        LOAD_X(s0, t0); LOAD_X(s1, t1);
    }

    for (int ts = 0; ts < T_LEN; ts += 2) {
        const int c2 = (ts + 2 < T_LEN) ? ts + 2 : T_LEN - 1;  // clamped (tail unused)
        const int c3 = (ts + 3 < T_LEN) ? ts + 3 : T_LEN - 1;
        const int tp0 = dir ? (T_LEN - 1 - ts) : ts;
        const int tp1 = dir ? (T_LEN - 2 - ts) : ts + 1;
        const int tn0 = dir ? (T_LEN - 1 - c2) : c2;
        const int tn1 = dir ? (T_LEN - 1 - c3) : c3;

        GRU_STEP(s0, 0, tp0, tn0);
        GRU_STEP(s1, 1, tp1, tn1);
    }
}

// ---------------------------------------------------------------------------
__device__ inline float softplus_f(float x) {
    return (x > 20.f) ? x : log1pf(__expf(x));
}

__global__ __launch_bounds__(256, 1)
void head_kernel(const __half* __restrict__ h1,
                 const float* __restrict__ mu_w, const float* __restrict__ mu_b,
                 const float* __restrict__ sg_w, const float* __restrict__ sg_b,
                 float* __restrict__ outp) {
    const int tid = threadIdx.x, lane = tid & 63, wv = tid >> 6;
    const int qq = lane >> 4, r16 = lane & 15;
    const int m0 = blockIdx.x * 128;

    __shared__ __align__(16) _Float16 Ws[32][520];
    __shared__ __align__(16) _Float16 Hs[128][40];

    {
        int rw = tid >> 3, c0 = (tid & 7) * 64;
        const float* src = (rw < 10) ? (mu_w + (size_t)rw * 512 + c0)
                         : (rw < 20) ? (sg_w + (size_t)(rw - 10) * 512 + c0) : nullptr;
        for (int cc = 0; cc < 64; cc += 8) {
            f16x8 hv;
            if (src) {
                f32x4 v0 = *reinterpret_cast<const f32x4*>(src + cc);
                f32x4 v1 = *reinterpret_cast<const f32x4*>(src + cc + 4);
#pragma unroll
                for (int j = 0; j < 4; ++j) { hv[j] = (_Float16)v0[j]; hv[4 + j] = (_Float16)v1[j]; }
            } else {
#pragma unroll
                for (int j = 0; j < 8; ++j) hv[j] = (_Float16)0.f;
            }
            *reinterpret_cast<f16x8*>(&Ws[rw][c0 + cc]) = hv;
        }
    }
    __syncthreads();

    f32x4 acc[2][2];
#pragma unroll
    for (int i = 0; i < 2; ++i)
#pragma unroll
        for (int j = 0; j < 2; ++j) acc[i][j] = (f32x4){0.f, 0.f, 0.f, 0.f};

    const int r = tid >> 1, seg = tid & 1;
    for (int kc = 0; kc < 16; ++kc) {
        const f16x8* hp = reinterpret_cast<const f16x8*>(h1 + (size_t)(m0 + r) * 512 + kc * 32 + 16 * seg);
        f16x8 h0 = hp[0], h1v = hp[1];
        *reinterpret_cast<f16x8*>(&Hs[r][16 * seg])     = h0;
        *reinterpret_cast<f16x8*>(&Hs[r][16 * seg + 8]) = h1v;
        __syncthreads();
        f16x8 af[2], bf[2];
#pragma unroll
        for (int mi = 0; mi < 2; ++mi)
            af[mi] = *reinterpret_cast<const f16x8*>(&Hs[wv * 32 + 16 * mi + r16][8 * qq]);
#pragma unroll
        for (int ni = 0; ni < 2; ++ni)
            bf[ni] = *reinterpret_cast<const f16x8*>(&Ws[16 * ni + r16][kc * 32 + 8 * qq]);
#pragma unroll
        for (int mi = 0; mi < 2; ++mi)
#pragma unroll
            for (int ni = 0; ni < 2; ++ni)
                acc[mi][ni] = __builtin_amdgcn_mfma_f32_16x16x32_f16(af[mi], bf[ni], acc[mi][ni], 0, 0, 0);
        __syncthreads();
    }

#pragma unroll
    for (int mi = 0; mi < 2; ++mi)
#pragma unroll
        for (int ni = 0; ni < 2; ++ni) {
            int ch = 16 * ni + r16;
#pragma unroll
            for (int rr = 0; rr < 4; ++rr) {
                int grow = m0 + wv * 32 + 16 * mi + 4 * qq + rr;
                float v = acc[mi][ni][rr];
                if (ch < 10) {
                    outp[(size_t)grow * 10 + ch] = v + mu_b[ch];
                } else if (ch < 20) {
                    outp[(size_t)T_LEN * 10 + (size_t)grow * 10 + (ch - 10)] = softplus_f(v + sg_b[ch - 10]);
                }
            }
        }
}

// ---------------------------------------------------------------------------
extern "C" void kernel_launch(void* const* d_in, const int* in_sizes, int n_in,
                              void* d_out, int out_size, void* d_ws, size_t ws_size,
                              hipStream_t stream) {
    const float* x      = (const float*)d_in[0];
    const float* wih_f0 = (const float*)d_in[1];
    const float* whh_f0 = (const float*)d_in[2];
    const float* b_f0   = (const float*)d_in[3];
    const float* bn_f0  = (const float*)d_in[4];
    const float* wih_b0 = (const float*)d_in[5];
    const float* whh_b0 = (const float*)d_in[6];
    const float* b_b0   = (const float*)d_in[7];
    const float* bn_b0  = (const float*)d_in[8];
    const float* wih_f1 = (const float*)d_in[9];
    const float* whh_f1 = (const float*)d_in[10];
    const float* b_f1   = (const float*)d_in[11];
    const float* bn_f1  = (const float*)d_in[12];
    const float* wih_b1 = (const float*)d_in[13];
    const float* whh_b1 = (const float*)d_in[14];
    const float* b_b1   = (const float*)d_in[15];
    const float* bn_b1  = (const float*)d_in[16];
    const float* mu_w   = (const float*)d_in[17];
    const float* mu_b   = (const float*)d_in[18];
    const float* sg_w   = (const float*)d_in[19];
    const float* sg_b   = (const float*)d_in[20];

    char* ws = (char*)d_ws;
    __half* xh     = (__half*)(ws);
    __half* iall_f = (__half*)(ws + (size_t)4 * 1024 * 1024);
    __half* iall_b = (__half*)(ws + (size_t)52 * 1024 * 1024);
    __half* out0   = (__half*)(ws + (size_t)100 * 1024 * 1024);
    __half* out1   = (__half*)(ws + (size_t)132 * 1024 * 1024);

    cvt_x_kernel<<<dim3((T_LEN * 64) / (256 * 8)), 256, 0, stream>>>(x, xh);
    gemm_f16_kernel<<<dim3(T_LEN / 128, 6, 2), 256, 0, stream>>>(xh, wih_f0, wih_b0, b_f0, b_b0, iall_f, iall_b, 64);
    recur_kernel<<<dim3(2), 512, 0, stream>>>(whh_f0, whh_b0, bn_f0, bn_b0, iall_f, iall_b, out0);
    gemm_f16_kernel<<<dim3(T_LEN / 128, 6, 2), 256, 0, stream>>>(out0, wih_f1, wih_b1, b_f1, b_b1, iall_f, iall_b, 512);
    recur_kernel<<<dim3(2), 512, 0, stream>>>(whh_f1, whh_b1, bn_f1, bn_b1, iall_f, iall_b, out1);
    head_kernel<<<dim3(T_LEN / 128), 256, 0, stream>>>(out1, mu_w, mu_b, sg_w, sg_b, (float*)d_out);
}